// Round 2
// baseline (1418.995 us; speedup 1.0000x reference)
//
#include <hip/hip_runtime.h>
#include <cstdio>

typedef unsigned short u16;
typedef unsigned int u32;
typedef unsigned long long u64;
typedef __attribute__((ext_vector_type(8))) short bf16x8;   // 8 x bf16 (4 VGPRs)
typedef __attribute__((ext_vector_type(4))) float f32x4;

#define NWG 128
#define TAG_STRIDE 8   // u32s per producer: 4 wave-tags + pad (32 B)

__device__ inline u16 f2bf(float x) {
  union { float f; unsigned u; } v; v.f = x;
  unsigned r = v.u + 0x7FFFu + ((v.u >> 16) & 1u);   // RNE
  return (u16)(r >> 16);
}
__device__ inline float sigm(float x) { return 1.0f / (1.0f + __expf(-x)); }
__device__ inline float tanh_fast(float x) { return 1.0f - 2.0f / (__expf(2.0f * x) + 1.0f); }

// ---------------- fp32 -> bf16 convert (vectorized) ----------------
__global__ __launch_bounds__(256) void k_convert(const float* __restrict__ in,
                                                 u16* __restrict__ out, int n4) {
  int i = blockIdx.x * blockDim.x + threadIdx.x;
  int stride = gridDim.x * blockDim.x;
  const float4* in4 = (const float4*)in;
  ushort4* out4 = (ushort4*)out;
  for (; i < n4; i += stride) {
    float4 v = in4[i];
    ushort4 o; o.x = f2bf(v.x); o.y = f2bf(v.y); o.z = f2bf(v.z); o.w = f2bf(v.w);
    out4[i] = o;
  }
}

// h0 -> h_bf buffer 0 (bf16), zero the per-(WG,wave) tags
__global__ __launch_bounds__(256) void k_init_h(const float* __restrict__ h0,
                                                u16* __restrict__ h_bf,
                                                u32* __restrict__ tags) {
  int i = blockIdx.x * blockDim.x + threadIdx.x;
  if (i < NWG * TAG_STRIDE) tags[i] = 0u;          // tag 0 == "h_0 available"
  if (i < 32768) h_bf[i] = f2bf(h0[i]);
}

// [R][C] fp32 -> [C][R] bf16 (tiled transpose)
__global__ __launch_bounds__(256) void k_transpose(const float* __restrict__ in,
                                                   u16* __restrict__ out, int R, int C) {
  __shared__ u16 tile[32][33];
  int tx = threadIdx.x & 31, ty = threadIdx.x >> 5;
  int c = blockIdx.x * 32 + tx;
  for (int i = 0; i < 32; i += 8) {
    int r = blockIdx.y * 32 + ty + i;
    tile[ty + i][tx] = f2bf(in[(size_t)r * C + c]);
  }
  __syncthreads();
  int r = blockIdx.y * 32 + tx;
  for (int i = 0; i < 32; i += 8) {
    int cc = blockIdx.x * 32 + ty + i;
    out[(size_t)cc * R + r] = tile[tx][ty + i];
  }
}

// ---------------- bf16 MFMA GEMM: C[M][N] = A[M][K] * BT[N][K]^T + bias ----------------
__global__ __launch_bounds__(256) void k_gemm_bt(const u16* __restrict__ A,
                                                 const u16* __restrict__ BT,
                                                 const float* __restrict__ bias,
                                                 float* __restrict__ C,
                                                 int M, int N, int K) {
  __shared__ u16 As[128][40];
  __shared__ u16 Bs[128][40];
  const int m0 = blockIdx.y * 128, n0 = blockIdx.x * 128;
  const int tid = threadIdx.x;
  const int lane = tid & 63, wave = tid >> 6;
  const int wm = (wave >> 1) * 64, wn = (wave & 1) * 64;
  const int lm = lane & 15, quad = lane >> 4;
  const int r = tid >> 1, kh = (tid & 1) * 16;

  f32x4 acc[4][4];
  for (int i = 0; i < 4; i++)
    for (int j = 0; j < 4; j++) acc[i][j] = (f32x4){0.f, 0.f, 0.f, 0.f};

  for (int k0 = 0; k0 < K; k0 += 32) {
    const uint4* ap = (const uint4*)(A + (size_t)(m0 + r) * K + k0 + kh);
    uint4 av0 = ap[0], av1 = ap[1];
    const uint4* bp = (const uint4*)(BT + (size_t)(n0 + r) * K + k0 + kh);
    uint4 bv0 = bp[0], bv1 = bp[1];
    __syncthreads();
    *(uint4*)&As[r][kh] = av0; *(uint4*)&As[r][kh + 8] = av1;
    *(uint4*)&Bs[r][kh] = bv0; *(uint4*)&Bs[r][kh + 8] = bv1;
    __syncthreads();
    bf16x8 a_frag[4], b_frag[4];
    for (int i = 0; i < 4; i++) a_frag[i] = *(const bf16x8*)&As[wm + i * 16 + lm][quad * 8];
    for (int j = 0; j < 4; j++) b_frag[j] = *(const bf16x8*)&Bs[wn + j * 16 + lm][quad * 8];
    for (int i = 0; i < 4; i++)
      for (int j = 0; j < 4; j++)
        acc[i][j] = __builtin_amdgcn_mfma_f32_16x16x32_bf16(a_frag[i], b_frag[j], acc[i][j], 0, 0, 0);
  }
  for (int i = 0; i < 4; i++)
    for (int j = 0; j < 4; j++) {
      int row = m0 + wm + i * 16 + quad * 4;
      int col = n0 + wn + j * 16 + lm;
      float bc = bias[col];
      for (int rr = 0; rr < 4; rr++)
        C[(size_t)(row + rr) * N + col] = acc[i][j][rr] + bc;
    }
}

// ---------------- persistent LSTM scan ----------------
// 128 WGs x 256 thr (1/CU). WG g owns h-cols [8g,8g+8) x 4 gates (32 packed cols).
// Sync protocol (v2.1, per-wave tags): producer wave w of WG g stores its 64 h
// values (agent scope), drains ITS OWN store with a per-wave vmcnt(0) (no WG
// barrier), then lane0 publishes tags[g][w] = t+1. Consumers: thread tid loads
// exactly the 4-col strip of producer g = tid>>1 (rows grouped by wave w), so
// it polls only that producer's 4 wave-tags and issues each 8xu64 row-group
// load the moment its tag passes -> data movement overlaps producer straggle.
// Poll has s_sleep(1) backoff on no-progress iterations only (bounds LLC port
// contention from 32K spinning threads; fast path pays nothing).
// ABA-safe: before WG g can write h_{t+2} (after B2 of step t+1) it passed B1
// of step t+1, whose strip loads collectively required ALL 128x4 tags >= t+1,
// i.e. every WG finished consuming h_t (2-buffer alternation).
// Only 2 barriers/step remain: B1 (h_lds ready; protects z_buf reuse) and
// B2 (z_buf ready; protects h_lds reuse).
__global__ __launch_bounds__(256) void k_lstm(const float* __restrict__ Z,    // [8192][4096]
                                              const u16* __restrict__ WhT,    // [4096][1024]
                                              const float* __restrict__ c0,   // [32][1024]
                                              u16* __restrict__ h_bf,         // [2][32][1024] bf16
                                              u16* __restrict__ Hs,           // [8192][1024] bf16
                                              float* __restrict__ out_c,
                                              float* __restrict__ out_h,
                                              u32* __restrict__ tags) {
  __shared__ u16 Whs[32][1032];      // 32 packed cols x K=1024 (+8 pad) = 66 KB
  __shared__ u16 h_lds[32][1032];    // h_t staged, 66 KB
  __shared__ float z_buf[32][34];    // [batch][packed col]
  const int g = blockIdx.x;
  const int tid = threadIdx.x;
  const int lane = tid & 63, wave = tid >> 6;
  const int lm = lane & 15, quad = lane >> 4;
  const int mhalf = wave >> 1, ntile = wave & 1;
  const int b = tid >> 3, jl = tid & 7;
  const u32 myg = (u32)(tid >> 1);   // the producer whose strip this thread loads

  // stage Wh^T slice: packed col pc -> WhT row (pc>>3)*1024 + 8g + (pc&7)
  {
    int pc = tid >> 3, seg = tid & 7;
    int grow = (pc >> 3) * 1024 + 8 * g + (pc & 7);
    const uint4* src = (const uint4*)(WhT + (size_t)grow * 1024 + seg * 128);
#pragma unroll
    for (int i = 0; i < 16; i++) {
      uint4 v = src[i];
      *(uint4*)&Whs[pc][seg * 128 + i * 8] = v;
    }
  }
  float creg = c0[b * 1024 + 8 * g + jl];   // this thread owns (b, col 8g+jl)

  for (int t = 0; t < 256; t++) {
    // 1. prefetch this step's Z contributions (L2/L3-cached; overlaps the poll)
    size_t zbase = ((size_t)b * 256 + t) * 4096 + 8 * g + jl;
    float z_i = Z[zbase], z_f = Z[zbase + 1024], z_g = Z[zbase + 2048], z_o = Z[zbase + 3072];

    // 2.+3. fine-grained arrival: poll my producer's 4 wave-tags; issue each
    //       8xu64 row-group load just-in-time as its tag passes.
    u64 v[32];
    {
      const u64* hq = (const u64*)(h_bf + (size_t)(t & 1) * 32768);
      const u32* tp = tags + myg * TAG_STRIDE;
      const u32 tgt = (u32)t;
      u32 pend = 0xFu;
      while (pend) {
        u32 got = 0;
#pragma unroll
        for (int w = 0; w < 4; w++)
          if (pend & (1u << w)) {
            u32 tv = __hip_atomic_load(tp + w, __ATOMIC_RELAXED, __HIP_MEMORY_SCOPE_AGENT);
            if (tv >= tgt) got |= (1u << w);
          }
        if (got) {
          asm volatile("" ::: "memory");  // data loads strictly after tag observation
#pragma unroll
          for (int w = 0; w < 4; w++)
            if (got & (1u << w)) {
#pragma unroll
              for (int j = 0; j < 8; j++)
                v[w * 8 + j] = __hip_atomic_load(hq + (w * 8 + j) * 256 + tid,
                                                 __ATOMIC_RELAXED, __HIP_MEMORY_SCOPE_AGENT);
            }
          pend &= ~got;
        } else {
          __builtin_amdgcn_s_sleep(1);   // backoff: keep LLC ports clear for producers
        }
      }
    }
#pragma unroll
    for (int i = 0; i < 32; i++)
      *(u64*)&h_lds[i][tid * 4] = v[i];
    __syncthreads();  // B1: h_lds (and, on t=0, Whs) ready; protects z_buf reuse

    // 4. MFMA: wave (mhalf,ntile) computes 16x16 block, K=1024, 4 ILP chains
    const u16* arow = &h_lds[mhalf * 16 + lm][quad * 8];
    const u16* brow = &Whs[ntile * 16 + lm][quad * 8];
    f32x4 a0 = (f32x4){0.f, 0.f, 0.f, 0.f}, a1 = a0, a2 = a0, a3 = a0;
#pragma unroll
    for (int ks = 0; ks < 32; ks += 4) {
      bf16x8 af0 = *(const bf16x8*)(arow + (ks + 0) * 32);
      bf16x8 bf0 = *(const bf16x8*)(brow + (ks + 0) * 32);
      bf16x8 af1 = *(const bf16x8*)(arow + (ks + 1) * 32);
      bf16x8 bf1 = *(const bf16x8*)(brow + (ks + 1) * 32);
      bf16x8 af2 = *(const bf16x8*)(arow + (ks + 2) * 32);
      bf16x8 bf2 = *(const bf16x8*)(brow + (ks + 2) * 32);
      bf16x8 af3 = *(const bf16x8*)(arow + (ks + 3) * 32);
      bf16x8 bf3 = *(const bf16x8*)(brow + (ks + 3) * 32);
      a0 = __builtin_amdgcn_mfma_f32_16x16x32_bf16(af0, bf0, a0, 0, 0, 0);
      a1 = __builtin_amdgcn_mfma_f32_16x16x32_bf16(af1, bf1, a1, 0, 0, 0);
      a2 = __builtin_amdgcn_mfma_f32_16x16x32_bf16(af2, bf2, a2, 0, 0, 0);
      a3 = __builtin_amdgcn_mfma_f32_16x16x32_bf16(af3, bf3, a3, 0, 0, 0);
    }
    f32x4 accs = (a0 + a1) + (a2 + a3);
    for (int rr = 0; rr < 4; rr++)
      z_buf[mhalf * 16 + quad * 4 + rr][ntile * 16 + lm] = accs[rr];
    __syncthreads();  // B2: z_buf ready; protects h_lds reuse

    // 5. gate math: one (b, col) per thread
    float zi = z_buf[b][jl]      + z_i;
    float zf = z_buf[b][8 + jl]  + z_f;
    float zg = z_buf[b][16 + jl] + z_g;
    float zo = z_buf[b][24 + jl] + z_o;
    float ig = sigm(zi), fg = sigm(zf), gg = tanh_fast(zg), og = sigm(zo);
    creg = fg * creg + ig * gg;
    float hv = og * tanh_fast(creg);
    u16 hb = f2bf(hv);

    // 6. per-wave publish: h store -> own-store drain -> wave tag. No barrier.
    __hip_atomic_store(h_bf + (size_t)((t + 1) & 1) * 32768 + b * 1024 + 8 * g + jl,
                       hb, __ATOMIC_RELAXED, __HIP_MEMORY_SCOPE_AGENT);
    asm volatile("s_waitcnt vmcnt(0)" ::: "memory");   // this wave's h store at LLC
    if (lane == 0)
      __hip_atomic_store(tags + g * TAG_STRIDE + wave, (u32)(t + 1),
                         __ATOMIC_RELAXED, __HIP_MEMORY_SCOPE_AGENT);

    // off the critical path: history store (+ final c/h at t=255)
    __builtin_nontemporal_store(hb, Hs + ((size_t)b * 256 + t) * 1024 + 8 * g + jl);
    if (t == 255) {
      out_c[b * 1024 + 8 * g + jl] = creg;
      out_h[b * 1024 + 8 * g + jl] = hv;
    }
  }
}

extern "C" void kernel_launch(void* const* d_in, const int* in_sizes, int n_in,
                              void* d_out, int out_size, void* d_ws, size_t ws_size,
                              hipStream_t stream) {
  const float* c0   = (const float*)d_in[0];
  const float* h0   = (const float*)d_in[1];
  const float* X    = (const float*)d_in[2];   // [32,256,1024]
  const float* Wi   = (const float*)d_in[3];   // [1024][4096]
  const float* Wh   = (const float*)d_in[4];   // [1024][4096]
  const float* bias = (const float*)d_in[5];   // [4096]
  const float* Wd   = (const float*)d_in[6];   // [1024][1024]
  const float* bd   = (const float*)d_in[7];   // [1024]
  float* out   = (float*)d_out;
  float* out_c = out;
  float* out_h = out + 32768;
  float* out_x = out + 65536;

  char* ws = (char*)d_ws;
  size_t off = 0;
  auto alloc = [&](size_t bytes) { char* p = ws + off; off += (bytes + 255) & ~255ull; return p; };
  float* Z     = (float*)alloc(134217728ull);   // [8192][4096] fp32
  u16*   Xb    = (u16*)alloc(16777216ull);      // [8192][1024] bf16
  u16*   WiT   = (u16*)alloc(8388608ull);       // [4096][1024] bf16
  u16*   WhT   = (u16*)alloc(8388608ull);       // [4096][1024] bf16
  u16*   WdT   = (u16*)alloc(2097152ull);       // [1024][1024] bf16
  u16*   Hs    = (u16*)alloc(16777216ull);      // [8192][1024] bf16
  u16*   h_bf  = (u16*)alloc(131072ull);        // [2][32][1024] bf16
  u32*   tags  = (u32*)alloc(NWG * TAG_STRIDE * 4);
  if (off > ws_size) {
    fprintf(stderr, "WS too small: need %zu have %zu\n", off, ws_size);
    return;
  }

  k_convert<<<2048, 256, 0, stream>>>(X, Xb, 8388608 / 4);
  k_init_h<<<128, 256, 0, stream>>>(h0, h_bf, tags);
  k_transpose<<<dim3(128, 32), 256, 0, stream>>>(Wi, WiT, 1024, 4096);
  k_transpose<<<dim3(128, 32), 256, 0, stream>>>(Wh, WhT, 1024, 4096);
  k_transpose<<<dim3(32, 32), 256, 0, stream>>>(Wd, WdT, 1024, 1024);
  k_gemm_bt<<<dim3(32, 64), 256, 0, stream>>>(Xb, WiT, bias, Z, 8192, 4096, 1024);
  k_lstm<<<NWG, 256, 0, stream>>>(Z, WhT, c0, h_bf, Hs, out_c, out_h, tags);
  k_gemm_bt<<<dim3(8, 64), 256, 0, stream>>>(Hs, WdT, bd, out_x, 8192, 1024, 1024);
}

// Round 3
// 1304.879 us; speedup vs baseline: 1.0875x; 1.0875x over previous
//
#include <hip/hip_runtime.h>
#include <cstdio>

typedef unsigned short u16;
typedef unsigned int u32;
typedef unsigned long long u64;
typedef __attribute__((ext_vector_type(8))) short bf16x8;   // 8 x bf16 (4 VGPRs)
typedef __attribute__((ext_vector_type(4))) float f32x4;

#define NWG 128
#define FLAG_STRIDE 32   // u32s -> 128 B between counters (own cacheline each)

__device__ inline u16 f2bf(float x) {
  union { float f; unsigned u; } v; v.f = x;
  unsigned r = v.u + 0x7FFFu + ((v.u >> 16) & 1u);   // RNE
  return (u16)(r >> 16);
}
__device__ inline float sigm(float x) { return 1.0f / (1.0f + __expf(-x)); }
__device__ inline float tanh_fast(float x) { return 1.0f - 2.0f / (__expf(2.0f * x) + 1.0f); }

// ---------------- fp32 -> bf16 convert (vectorized) ----------------
__global__ __launch_bounds__(256) void k_convert(const float* __restrict__ in,
                                                 u16* __restrict__ out, int n4) {
  int i = blockIdx.x * blockDim.x + threadIdx.x;
  int stride = gridDim.x * blockDim.x;
  const float4* in4 = (const float4*)in;
  ushort4* out4 = (ushort4*)out;
  for (; i < n4; i += stride) {
    float4 v = in4[i];
    ushort4 o; o.x = f2bf(v.x); o.y = f2bf(v.y); o.z = f2bf(v.z); o.w = f2bf(v.w);
    out4[i] = o;
  }
}

// h0 -> h_bf buffer 0 (bf16), zero the per-WG counters
__global__ __launch_bounds__(256) void k_init_h(const float* __restrict__ h0,
                                                u16* __restrict__ h_bf,
                                                u32* __restrict__ flags) {
  int i = blockIdx.x * blockDim.x + threadIdx.x;
  if (i < NWG * FLAG_STRIDE) flags[i] = 0u;        // counter 0 == "h_0 available"
  if (i < 32768) h_bf[i] = f2bf(h0[i]);
}

// [R][C] fp32 -> [C][R] bf16 (tiled transpose)
__global__ __launch_bounds__(256) void k_transpose(const float* __restrict__ in,
                                                   u16* __restrict__ out, int R, int C) {
  __shared__ u16 tile[32][33];
  int tx = threadIdx.x & 31, ty = threadIdx.x >> 5;
  int c = blockIdx.x * 32 + tx;
  for (int i = 0; i < 32; i += 8) {
    int r = blockIdx.y * 32 + ty + i;
    tile[ty + i][tx] = f2bf(in[(size_t)r * C + c]);
  }
  __syncthreads();
  int r = blockIdx.y * 32 + tx;
  for (int i = 0; i < 32; i += 8) {
    int cc = blockIdx.x * 32 + ty + i;
    out[(size_t)cc * R + r] = tile[tx][ty + i];
  }
}

// ---------------- bf16 MFMA GEMM: C[M][N] = A[M][K] * BT[N][K]^T + bias ----------------
__global__ __launch_bounds__(256) void k_gemm_bt(const u16* __restrict__ A,
                                                 const u16* __restrict__ BT,
                                                 const float* __restrict__ bias,
                                                 float* __restrict__ C,
                                                 int M, int N, int K) {
  __shared__ u16 As[128][40];
  __shared__ u16 Bs[128][40];
  const int m0 = blockIdx.y * 128, n0 = blockIdx.x * 128;
  const int tid = threadIdx.x;
  const int lane = tid & 63, wave = tid >> 6;
  const int wm = (wave >> 1) * 64, wn = (wave & 1) * 64;
  const int lm = lane & 15, quad = lane >> 4;
  const int r = tid >> 1, kh = (tid & 1) * 16;

  f32x4 acc[4][4];
  for (int i = 0; i < 4; i++)
    for (int j = 0; j < 4; j++) acc[i][j] = (f32x4){0.f, 0.f, 0.f, 0.f};

  for (int k0 = 0; k0 < K; k0 += 32) {
    const uint4* ap = (const uint4*)(A + (size_t)(m0 + r) * K + k0 + kh);
    uint4 av0 = ap[0], av1 = ap[1];
    const uint4* bp = (const uint4*)(BT + (size_t)(n0 + r) * K + k0 + kh);
    uint4 bv0 = bp[0], bv1 = bp[1];
    __syncthreads();
    *(uint4*)&As[r][kh] = av0; *(uint4*)&As[r][kh + 8] = av1;
    *(uint4*)&Bs[r][kh] = bv0; *(uint4*)&Bs[r][kh + 8] = bv1;
    __syncthreads();
    bf16x8 a_frag[4], b_frag[4];
    for (int i = 0; i < 4; i++) a_frag[i] = *(const bf16x8*)&As[wm + i * 16 + lm][quad * 8];
    for (int j = 0; j < 4; j++) b_frag[j] = *(const bf16x8*)&Bs[wn + j * 16 + lm][quad * 8];
    for (int i = 0; i < 4; i++)
      for (int j = 0; j < 4; j++)
        acc[i][j] = __builtin_amdgcn_mfma_f32_16x16x32_bf16(a_frag[i], b_frag[j], acc[i][j], 0, 0, 0);
  }
  for (int i = 0; i < 4; i++)
    for (int j = 0; j < 4; j++) {
      int row = m0 + wm + i * 16 + quad * 4;
      int col = n0 + wn + j * 16 + lm;
      float bc = bias[col];
      for (int rr = 0; rr < 4; rr++)
        C[(size_t)(row + rr) * N + col] = acc[i][j][rr] + bc;
    }
}

// ---------------- persistent LSTM scan ----------------
// 128 WGs x 256 thr (1/CU). WG g owns h-cols [8g,8g+8) x 4 gates (32 packed cols).
// v3 protocol: v1's consumer structure (uniform WG-wide poll -> bulk coalesced
// 32xu64 h load) + per-wave publish (no B3 barrier): each wave stores its 64 h
// values (agent scope), drains ITS OWN stores with a per-wave vmcnt(0), then
// lane0 atomically bumps the per-WG counter. Consumer waits counter >= 4t for
// all 128 producers. The nontemporal Hs store (slow HBM ack) moved AFTER the
// publish, off the critical path.
// ABA-safe (one-deep): counter[g] >= 4t  ==>  all 4 waves of g drained h_t
// stores ==> g finished loading h_{t-1}. Before WG A can write h_{t+1} it
// observed all counters >= 4t ==> every WG done reading buf[(t+1)&1].
// LDS hazards without B3: a thread's step-t+1 h_lds write is gated on the poll
// seeing its OWN WG's counter >= 4(t+1), which requires all local waves past
// B2+gates of step t ==> no wave can still be reading h_lds/z_buf of step t.
__global__ __launch_bounds__(256) void k_lstm(const float* __restrict__ Z,    // [8192][4096]
                                              const u16* __restrict__ WhT,    // [4096][1024]
                                              const float* __restrict__ c0,   // [32][1024]
                                              u16* __restrict__ h_bf,         // [2][32][1024] bf16
                                              u16* __restrict__ Hs,           // [8192][1024] bf16
                                              float* __restrict__ out_c,
                                              float* __restrict__ out_h,
                                              u32* __restrict__ flags) {
  __shared__ u16 Whs[32][1032];      // 32 packed cols x K=1024 (+8 pad) = 66 KB
  __shared__ u16 h_lds[32][1032];    // h_t staged, 66 KB
  __shared__ float z_buf[32][34];    // [batch][packed col]
  const int g = blockIdx.x;
  const int tid = threadIdx.x;
  const int lane = tid & 63, wave = tid >> 6;
  const int lm = lane & 15, quad = lane >> 4;
  const int mhalf = wave >> 1, ntile = wave & 1;
  const int b = tid >> 3, jl = tid & 7;

  // stage Wh^T slice: packed col pc -> WhT row (pc>>3)*1024 + 8g + (pc&7)
  {
    int pc = tid >> 3, seg = tid & 7;
    int grow = (pc >> 3) * 1024 + 8 * g + (pc & 7);
    const uint4* src = (const uint4*)(WhT + (size_t)grow * 1024 + seg * 128);
#pragma unroll
    for (int i = 0; i < 16; i++) {
      uint4 v = src[i];
      *(uint4*)&Whs[pc][seg * 128 + i * 8] = v;
    }
  }
  float creg = c0[b * 1024 + 8 * g + jl];   // this thread owns (b, col 8g+jl)

  for (int t = 0; t < 256; t++) {
    // 1. prefetch this step's Z contributions (L2/L3-cached; overlaps the poll)
    size_t zbase = ((size_t)b * 256 + t) * 4096 + 8 * g + jl;
    float z_i = Z[zbase], z_f = Z[zbase + 1024], z_g = Z[zbase + 2048], z_o = Z[zbase + 3072];

    // 2. all waves poll all 128 counters (2 per lane), coherent relaxed loads
    {
      const u32 tgt = (u32)(4 * t);
      const u32* f0 = flags + lane * FLAG_STRIDE;
      const u32* f1 = flags + (lane + 64) * FLAG_STRIDE;
      while (true) {
        u32 v0 = __hip_atomic_load(f0, __ATOMIC_RELAXED, __HIP_MEMORY_SCOPE_AGENT);
        u32 v1 = __hip_atomic_load(f1, __ATOMIC_RELAXED, __HIP_MEMORY_SCOPE_AGENT);
        if (__all((v0 >= tgt) && (v1 >= tgt))) break;
        __builtin_amdgcn_s_sleep(1);
      }
      asm volatile("" ::: "memory");  // no hoisting of h loads above the poll
    }

    // 3. stage h_t -> LDS: 32 coherent u64 loads/thread, fully preloaded,
    //    perfectly coalesced (consecutive tids -> consecutive u64s)
    {
      const u64* hq = (const u64*)(h_bf + (size_t)(t & 1) * 32768);
      u64 v[32];
#pragma unroll
      for (int i = 0; i < 32; i++)
        v[i] = __hip_atomic_load(hq + i * 256 + tid, __ATOMIC_RELAXED, __HIP_MEMORY_SCOPE_AGENT);
#pragma unroll
      for (int i = 0; i < 32; i++) {
        int q = i * 256 + tid;
        *(u64*)&h_lds[q >> 8][(q & 255) * 4] = v[i];
      }
    }
    __syncthreads();  // B1: h_lds (and, on t=0, Whs) ready

    // 4. MFMA: wave (mhalf,ntile) computes 16x16 block, K=1024, 4 ILP chains
    const u16* arow = &h_lds[mhalf * 16 + lm][quad * 8];
    const u16* brow = &Whs[ntile * 16 + lm][quad * 8];
    f32x4 a0 = (f32x4){0.f, 0.f, 0.f, 0.f}, a1 = a0, a2 = a0, a3 = a0;
#pragma unroll
    for (int ks = 0; ks < 32; ks += 4) {
      bf16x8 af0 = *(const bf16x8*)(arow + (ks + 0) * 32);
      bf16x8 bf0 = *(const bf16x8*)(brow + (ks + 0) * 32);
      bf16x8 af1 = *(const bf16x8*)(arow + (ks + 1) * 32);
      bf16x8 bf1 = *(const bf16x8*)(brow + (ks + 1) * 32);
      bf16x8 af2 = *(const bf16x8*)(arow + (ks + 2) * 32);
      bf16x8 bf2 = *(const bf16x8*)(brow + (ks + 2) * 32);
      bf16x8 af3 = *(const bf16x8*)(arow + (ks + 3) * 32);
      bf16x8 bf3 = *(const bf16x8*)(brow + (ks + 3) * 32);
      a0 = __builtin_amdgcn_mfma_f32_16x16x32_bf16(af0, bf0, a0, 0, 0, 0);
      a1 = __builtin_amdgcn_mfma_f32_16x16x32_bf16(af1, bf1, a1, 0, 0, 0);
      a2 = __builtin_amdgcn_mfma_f32_16x16x32_bf16(af2, bf2, a2, 0, 0, 0);
      a3 = __builtin_amdgcn_mfma_f32_16x16x32_bf16(af3, bf3, a3, 0, 0, 0);
    }
    f32x4 accs = (a0 + a1) + (a2 + a3);
    for (int rr = 0; rr < 4; rr++)
      z_buf[mhalf * 16 + quad * 4 + rr][ntile * 16 + lm] = accs[rr];
    __syncthreads();  // B2: z_buf ready; protects h_lds reuse

    // 5. gate math: one (b, col) per thread
    float zi = z_buf[b][jl]      + z_i;
    float zf = z_buf[b][8 + jl]  + z_f;
    float zg = z_buf[b][16 + jl] + z_g;
    float zo = z_buf[b][24 + jl] + z_o;
    float ig = sigm(zi), fg = sigm(zf), gg = tanh_fast(zg), og = sigm(zo);
    creg = fg * creg + ig * gg;
    float hv = og * tanh_fast(creg);
    u16 hb = f2bf(hv);

    // 6. per-wave publish: h store -> own-store drain -> counter bump. No barrier.
    __hip_atomic_store(h_bf + (size_t)((t + 1) & 1) * 32768 + b * 1024 + 8 * g + jl,
                       hb, __ATOMIC_RELAXED, __HIP_MEMORY_SCOPE_AGENT);
    asm volatile("s_waitcnt vmcnt(0)" ::: "memory");   // this wave's h store at LLC
    if (lane == 0)
      __hip_atomic_fetch_add(flags + g * FLAG_STRIDE, 1u,
                             __ATOMIC_RELAXED, __HIP_MEMORY_SCOPE_AGENT);

    // off the critical path: history store (+ final c/h at t=255)
    __builtin_nontemporal_store(hb, Hs + ((size_t)b * 256 + t) * 1024 + 8 * g + jl);
    if (t == 255) {
      out_c[b * 1024 + 8 * g + jl] = creg;
      out_h[b * 1024 + 8 * g + jl] = hv;
    }
  }
}

extern "C" void kernel_launch(void* const* d_in, const int* in_sizes, int n_in,
                              void* d_out, int out_size, void* d_ws, size_t ws_size,
                              hipStream_t stream) {
  const float* c0   = (const float*)d_in[0];
  const float* h0   = (const float*)d_in[1];
  const float* X    = (const float*)d_in[2];   // [32,256,1024]
  const float* Wi   = (const float*)d_in[3];   // [1024][4096]
  const float* Wh   = (const float*)d_in[4];   // [1024][4096]
  const float* bias = (const float*)d_in[5];   // [4096]
  const float* Wd   = (const float*)d_in[6];   // [1024][1024]
  const float* bd   = (const float*)d_in[7];   // [1024]
  float* out   = (float*)d_out;
  float* out_c = out;
  float* out_h = out + 32768;
  float* out_x = out + 65536;

  char* ws = (char*)d_ws;
  size_t off = 0;
  auto alloc = [&](size_t bytes) { char* p = ws + off; off += (bytes + 255) & ~255ull; return p; };
  float* Z     = (float*)alloc(134217728ull);   // [8192][4096] fp32
  u16*   Xb    = (u16*)alloc(16777216ull);      // [8192][1024] bf16
  u16*   WiT   = (u16*)alloc(8388608ull);       // [4096][1024] bf16
  u16*   WhT   = (u16*)alloc(8388608ull);       // [4096][1024] bf16
  u16*   WdT   = (u16*)alloc(2097152ull);       // [1024][1024] bf16
  u16*   Hs    = (u16*)alloc(16777216ull);      // [8192][1024] bf16
  u16*   h_bf  = (u16*)alloc(131072ull);        // [2][32][1024] bf16
  u32*   flags = (u32*)alloc(NWG * FLAG_STRIDE * 4);
  if (off > ws_size) {
    fprintf(stderr, "WS too small: need %zu have %zu\n", off, ws_size);
    return;
  }

  k_convert<<<2048, 256, 0, stream>>>(X, Xb, 8388608 / 4);
  k_init_h<<<128, 256, 0, stream>>>(h0, h_bf, flags);
  k_transpose<<<dim3(128, 32), 256, 0, stream>>>(Wi, WiT, 1024, 4096);
  k_transpose<<<dim3(128, 32), 256, 0, stream>>>(Wh, WhT, 1024, 4096);
  k_transpose<<<dim3(32, 32), 256, 0, stream>>>(Wd, WdT, 1024, 1024);
  k_gemm_bt<<<dim3(32, 64), 256, 0, stream>>>(Xb, WiT, bias, Z, 8192, 4096, 1024);
  k_lstm<<<NWG, 256, 0, stream>>>(Z, WhT, c0, h_bf, Hs, out_c, out_h, flags);
  k_gemm_bt<<<dim3(8, 64), 256, 0, stream>>>(Hs, WdT, bd, out_x, 8192, 1024, 1024);
}

// Round 4
// 1187.630 us; speedup vs baseline: 1.1948x; 1.0987x over previous
//
#include <hip/hip_runtime.h>
#include <cstdio>

typedef unsigned short u16;
typedef unsigned int u32;
typedef unsigned long long u64;
typedef __attribute__((ext_vector_type(8))) short bf16x8;   // 8 x bf16 (4 VGPRs)
typedef __attribute__((ext_vector_type(4))) float f32x4;

#define NWG 128

__device__ inline u16 f2bf(float x) {
  union { float f; unsigned u; } v; v.f = x;
  unsigned r = v.u + 0x7FFFu + ((v.u >> 16) & 1u);   // RNE
  return (u16)(r >> 16);
}
__device__ inline float sigm(float x) { return 1.0f / (1.0f + __expf(-x)); }
__device__ inline float tanh_fast(float x) { return 1.0f - 2.0f / (__expf(2.0f * x) + 1.0f); }

// ---------------- fp32 -> bf16 convert (vectorized) ----------------
__global__ __launch_bounds__(256) void k_convert(const float* __restrict__ in,
                                                 u16* __restrict__ out, int n4) {
  int i = blockIdx.x * blockDim.x + threadIdx.x;
  int stride = gridDim.x * blockDim.x;
  const float4* in4 = (const float4*)in;
  ushort4* out4 = (ushort4*)out;
  for (; i < n4; i += stride) {
    float4 v = in4[i];
    ushort4 o; o.x = f2bf(v.x); o.y = f2bf(v.y); o.z = f2bf(v.z); o.w = f2bf(v.w);
    out4[i] = o;
  }
}

// h0 -> h_bf buffer 0 (bf16), zero the packed per-WG flags
__global__ __launch_bounds__(256) void k_init_h(const float* __restrict__ h0,
                                                u16* __restrict__ h_bf,
                                                u32* __restrict__ flags) {
  int i = blockIdx.x * blockDim.x + threadIdx.x;
  if (i < NWG) flags[i] = 0u;          // flag t == "h_t available"
  if (i < 32768) h_bf[i] = f2bf(h0[i]);
}

// [R][C] fp32 -> [C][R] bf16 (tiled transpose)
__global__ __launch_bounds__(256) void k_transpose(const float* __restrict__ in,
                                                   u16* __restrict__ out, int R, int C) {
  __shared__ u16 tile[32][33];
  int tx = threadIdx.x & 31, ty = threadIdx.x >> 5;
  int c = blockIdx.x * 32 + tx;
  for (int i = 0; i < 32; i += 8) {
    int r = blockIdx.y * 32 + ty + i;
    tile[ty + i][tx] = f2bf(in[(size_t)r * C + c]);
  }
  __syncthreads();
  int r = blockIdx.y * 32 + tx;
  for (int i = 0; i < 32; i += 8) {
    int cc = blockIdx.x * 32 + ty + i;
    out[(size_t)cc * R + r] = tile[tx][ty + i];
  }
}

// ---------------- bf16 MFMA GEMM: C[M][N] = A[M][K] * BT[N][K]^T + bias ----------------
__global__ __launch_bounds__(256) void k_gemm_bt(const u16* __restrict__ A,
                                                 const u16* __restrict__ BT,
                                                 const float* __restrict__ bias,
                                                 float* __restrict__ C,
                                                 int M, int N, int K) {
  __shared__ u16 As[128][40];
  __shared__ u16 Bs[128][40];
  const int m0 = blockIdx.y * 128, n0 = blockIdx.x * 128;
  const int tid = threadIdx.x;
  const int lane = tid & 63, wave = tid >> 6;
  const int wm = (wave >> 1) * 64, wn = (wave & 1) * 64;
  const int lm = lane & 15, quad = lane >> 4;
  const int r = tid >> 1, kh = (tid & 1) * 16;

  f32x4 acc[4][4];
  for (int i = 0; i < 4; i++)
    for (int j = 0; j < 4; j++) acc[i][j] = (f32x4){0.f, 0.f, 0.f, 0.f};

  for (int k0 = 0; k0 < K; k0 += 32) {
    const uint4* ap = (const uint4*)(A + (size_t)(m0 + r) * K + k0 + kh);
    uint4 av0 = ap[0], av1 = ap[1];
    const uint4* bp = (const uint4*)(BT + (size_t)(n0 + r) * K + k0 + kh);
    uint4 bv0 = bp[0], bv1 = bp[1];
    __syncthreads();
    *(uint4*)&As[r][kh] = av0; *(uint4*)&As[r][kh + 8] = av1;
    *(uint4*)&Bs[r][kh] = bv0; *(uint4*)&Bs[r][kh + 8] = bv1;
    __syncthreads();
    bf16x8 a_frag[4], b_frag[4];
    for (int i = 0; i < 4; i++) a_frag[i] = *(const bf16x8*)&As[wm + i * 16 + lm][quad * 8];
    for (int j = 0; j < 4; j++) b_frag[j] = *(const bf16x8*)&Bs[wn + j * 16 + lm][quad * 8];
    for (int i = 0; i < 4; i++)
      for (int j = 0; j < 4; j++)
        acc[i][j] = __builtin_amdgcn_mfma_f32_16x16x32_bf16(a_frag[i], b_frag[j], acc[i][j], 0, 0, 0);
  }
  for (int i = 0; i < 4; i++)
    for (int j = 0; j < 4; j++) {
      int row = m0 + wm + i * 16 + quad * 4;
      int col = n0 + wn + j * 16 + lm;
      float bc = bias[col];
      for (int rr = 0; rr < 4; rr++)
        C[(size_t)(row + rr) * N + col] = acc[i][j][rr] + bc;
    }
}

// ---------------- persistent LSTM scan ----------------
// 128 WGs x 256 thr (1/CU). WG g owns h-cols [8g,8g+8) x 4 gates (32 packed cols).
// v4 = v1 protocol (B3 barrier + ONE plain flag store per WG -- measured best;
// per-wave RMW publish regressed in v2/v3) with two off-path fixes:
//  (a) flags PACKED contiguously (128 u32 = 4 cachelines): each wave's poll is
//      2 coalesced dword loads touching 4 lines total, vs 128-line scatter at
//      FLAG_STRIDE=32 -> 32x less LLC poll traffic contending with h stores.
//  (b) Hs nontemporal store (HBM-ack) and t==255 outputs moved AFTER the flag
//      publish, so B3's vmcnt(0) drain no longer waits on HBM write acks.
// NO fences: h + flags move via agent-scope accesses only; L2 never
// invalidated, so Z stays cached. h staged to LDS once per step per WG.
__global__ __launch_bounds__(256) void k_lstm(const float* __restrict__ Z,    // [8192][4096]
                                              const u16* __restrict__ WhT,    // [4096][1024]
                                              const float* __restrict__ c0,   // [32][1024]
                                              u16* __restrict__ h_bf,         // [2][32][1024] bf16
                                              u16* __restrict__ Hs,           // [8192][1024] bf16
                                              float* __restrict__ out_c,
                                              float* __restrict__ out_h,
                                              u32* __restrict__ flags) {
  __shared__ u16 Whs[32][1032];      // 32 packed cols x K=1024 (+8 pad) = 66 KB
  __shared__ u16 h_lds[32][1032];    // h_t staged, 66 KB
  __shared__ float z_buf[32][34];    // [batch][packed col]
  const int g = blockIdx.x;
  const int tid = threadIdx.x;
  const int lane = tid & 63, wave = tid >> 6;
  const int lm = lane & 15, quad = lane >> 4;
  const int mhalf = wave >> 1, ntile = wave & 1;
  const int b = tid >> 3, jl = tid & 7;

  // stage Wh^T slice: packed col pc -> WhT row (pc>>3)*1024 + 8g + (pc&7)
  {
    int pc = tid >> 3, seg = tid & 7;
    int grow = (pc >> 3) * 1024 + 8 * g + (pc & 7);
    const uint4* src = (const uint4*)(WhT + (size_t)grow * 1024 + seg * 128);
#pragma unroll
    for (int i = 0; i < 16; i++) {
      uint4 v = src[i];
      *(uint4*)&Whs[pc][seg * 128 + i * 8] = v;
    }
  }
  float creg = c0[b * 1024 + 8 * g + jl];   // this thread owns (b, col 8g+jl)

  for (int t = 0; t < 256; t++) {
    // 1. prefetch this step's Z contributions (L2/L3-cached; overlaps the poll)
    size_t zbase = ((size_t)b * 256 + t) * 4096 + 8 * g + jl;
    float z_i = Z[zbase], z_f = Z[zbase + 1024], z_g = Z[zbase + 2048], z_o = Z[zbase + 3072];

    // 2. all waves poll all 128 flags (2 per lane), coherent relaxed loads.
    //    Packed flags: both loads coalesce; whole poll touches 4 cachelines.
    {
      const u32 tgt = (u32)t;
      const u32* f0 = flags + lane;
      const u32* f1 = flags + 64 + lane;
      while (true) {
        u32 v0 = __hip_atomic_load(f0, __ATOMIC_RELAXED, __HIP_MEMORY_SCOPE_AGENT);
        u32 v1 = __hip_atomic_load(f1, __ATOMIC_RELAXED, __HIP_MEMORY_SCOPE_AGENT);
        if (__all((v0 >= tgt) && (v1 >= tgt))) break;
        __builtin_amdgcn_s_sleep(1);
      }
      asm volatile("" ::: "memory");  // no hoisting of h loads above the poll
    }

    // 3. stage h_t -> LDS: 32 coherent u64 loads/thread, fully preloaded,
    //    perfectly coalesced (consecutive tids -> consecutive u64s)
    {
      const u64* hq = (const u64*)(h_bf + (size_t)(t & 1) * 32768);
      u64 v[32];
#pragma unroll
      for (int i = 0; i < 32; i++)
        v[i] = __hip_atomic_load(hq + i * 256 + tid, __ATOMIC_RELAXED, __HIP_MEMORY_SCOPE_AGENT);
#pragma unroll
      for (int i = 0; i < 32; i++) {
        int q = i * 256 + tid;
        *(u64*)&h_lds[q >> 8][(q & 255) * 4] = v[i];
      }
    }
    __syncthreads();  // B1: h_lds (and, on t=0, Whs) ready

    // 4. MFMA: wave (mhalf,ntile) computes 16x16 block, K=1024, 4 ILP chains
    const u16* arow = &h_lds[mhalf * 16 + lm][quad * 8];
    const u16* brow = &Whs[ntile * 16 + lm][quad * 8];
    f32x4 a0 = (f32x4){0.f, 0.f, 0.f, 0.f}, a1 = a0, a2 = a0, a3 = a0;
#pragma unroll
    for (int ks = 0; ks < 32; ks += 4) {
      bf16x8 af0 = *(const bf16x8*)(arow + (ks + 0) * 32);
      bf16x8 bf0 = *(const bf16x8*)(brow + (ks + 0) * 32);
      bf16x8 af1 = *(const bf16x8*)(arow + (ks + 1) * 32);
      bf16x8 bf1 = *(const bf16x8*)(brow + (ks + 1) * 32);
      bf16x8 af2 = *(const bf16x8*)(arow + (ks + 2) * 32);
      bf16x8 bf2 = *(const bf16x8*)(brow + (ks + 2) * 32);
      bf16x8 af3 = *(const bf16x8*)(arow + (ks + 3) * 32);
      bf16x8 bf3 = *(const bf16x8*)(brow + (ks + 3) * 32);
      a0 = __builtin_amdgcn_mfma_f32_16x16x32_bf16(af0, bf0, a0, 0, 0, 0);
      a1 = __builtin_amdgcn_mfma_f32_16x16x32_bf16(af1, bf1, a1, 0, 0, 0);
      a2 = __builtin_amdgcn_mfma_f32_16x16x32_bf16(af2, bf2, a2, 0, 0, 0);
      a3 = __builtin_amdgcn_mfma_f32_16x16x32_bf16(af3, bf3, a3, 0, 0, 0);
    }
    f32x4 accs = (a0 + a1) + (a2 + a3);
    for (int rr = 0; rr < 4; rr++)
      z_buf[mhalf * 16 + quad * 4 + rr][ntile * 16 + lm] = accs[rr];
    __syncthreads();  // B2: z_buf ready

    // 5. gate math: one (b, col) per thread
    float zi = z_buf[b][jl]      + z_i;
    float zf = z_buf[b][8 + jl]  + z_f;
    float zg = z_buf[b][16 + jl] + z_g;
    float zo = z_buf[b][24 + jl] + z_o;
    float ig = sigm(zi), fg = sigm(zf), gg = tanh_fast(zg), og = sigm(zo);
    creg = fg * creg + ig * gg;
    float hv = og * tanh_fast(creg);
    u16 hb = f2bf(hv);
    // publish h write-through to the coherence point (no L2 residency)
    __hip_atomic_store(h_bf + (size_t)((t + 1) & 1) * 32768 + b * 1024 + 8 * g + jl,
                       hb, __ATOMIC_RELAXED, __HIP_MEMORY_SCOPE_AGENT);
    __syncthreads();  // B3: per-wave vmcnt drain -> all h stores at LLC
    if (tid == 0)
      __hip_atomic_store(flags + g, (u32)(t + 1),
                         __ATOMIC_RELAXED, __HIP_MEMORY_SCOPE_AGENT);

    // off the critical path: history store (+ final c/h at t=255) AFTER publish
    __builtin_nontemporal_store(hb, Hs + ((size_t)b * 256 + t) * 1024 + 8 * g + jl);
    if (t == 255) {
      out_c[b * 1024 + 8 * g + jl] = creg;
      out_h[b * 1024 + 8 * g + jl] = hv;
    }
  }
}

extern "C" void kernel_launch(void* const* d_in, const int* in_sizes, int n_in,
                              void* d_out, int out_size, void* d_ws, size_t ws_size,
                              hipStream_t stream) {
  const float* c0   = (const float*)d_in[0];
  const float* h0   = (const float*)d_in[1];
  const float* X    = (const float*)d_in[2];   // [32,256,1024]
  const float* Wi   = (const float*)d_in[3];   // [1024][4096]
  const float* Wh   = (const float*)d_in[4];   // [1024][4096]
  const float* bias = (const float*)d_in[5];   // [4096]
  const float* Wd   = (const float*)d_in[6];   // [1024][1024]
  const float* bd   = (const float*)d_in[7];   // [1024]
  float* out   = (float*)d_out;
  float* out_c = out;
  float* out_h = out + 32768;
  float* out_x = out + 65536;

  char* ws = (char*)d_ws;
  size_t off = 0;
  auto alloc = [&](size_t bytes) { char* p = ws + off; off += (bytes + 255) & ~255ull; return p; };
  float* Z     = (float*)alloc(134217728ull);   // [8192][4096] fp32
  u16*   Xb    = (u16*)alloc(16777216ull);      // [8192][1024] bf16
  u16*   WiT   = (u16*)alloc(8388608ull);       // [4096][1024] bf16
  u16*   WhT   = (u16*)alloc(8388608ull);       // [4096][1024] bf16
  u16*   WdT   = (u16*)alloc(2097152ull);       // [1024][1024] bf16
  u16*   Hs    = (u16*)alloc(16777216ull);      // [8192][1024] bf16
  u16*   h_bf  = (u16*)alloc(131072ull);        // [2][32][1024] bf16
  u32*   flags = (u32*)alloc(NWG * 4);
  if (off > ws_size) {
    fprintf(stderr, "WS too small: need %zu have %zu\n", off, ws_size);
    return;
  }

  k_convert<<<2048, 256, 0, stream>>>(X, Xb, 8388608 / 4);
  k_init_h<<<128, 256, 0, stream>>>(h0, h_bf, flags);
  k_transpose<<<dim3(128, 32), 256, 0, stream>>>(Wi, WiT, 1024, 4096);
  k_transpose<<<dim3(128, 32), 256, 0, stream>>>(Wh, WhT, 1024, 4096);
  k_transpose<<<dim3(32, 32), 256, 0, stream>>>(Wd, WdT, 1024, 1024);
  k_gemm_bt<<<dim3(32, 64), 256, 0, stream>>>(Xb, WiT, bias, Z, 8192, 4096, 1024);
  k_lstm<<<NWG, 256, 0, stream>>>(Z, WhT, c0, h_bf, Hs, out_c, out_h, flags);
  k_gemm_bt<<<dim3(8, 64), 256, 0, stream>>>(Hs, WdT, bd, out_x, 8192, 1024, 1024);
}